// Round 16
// baseline (217.499 us; speedup 1.0000x reference)
//
#include <hip/hip_runtime.h>

#define N_NODES   50000
#define N_EDGES   800000
#define NEG_SLOPE 0.2f
#define NBKT      256          // coarse buckets
#define NPB       196          // nodes per bucket (196*256 = 50176 >= 50000)
#define EPB       3125         // edges per binscatter block (800000/256)
#define CAP       4096         // fixed bucket capacity (true ~3136 +- 56; 17 sigma)
#define G1BLK     782          // gemm1 blocks: ceil(50000/64)

__device__ __forceinline__ float leaky(float x) {
    return x > 0.f ? x : x * NEG_SLOPE;
}

__device__ __forceinline__ unsigned short f2bf(float f) {   // RNE pack
    unsigned int u = __float_as_uint(f);
    unsigned int r = (u + 0x7FFFu + ((u >> 16) & 1u)) >> 16;
    return (unsigned short)r;
}

__device__ __forceinline__ unsigned int pack2bf(float a, float b) {
    return (unsigned int)f2bf(a) | ((unsigned int)f2bf(b) << 16);
}

__device__ __forceinline__ float2 bf2f2(unsigned int p) {   // packed bf16x2 -> float2
    return make_float2(__uint_as_float(p << 16),
                       __uint_as_float(p & 0xFFFF0000u));
}

__device__ __forceinline__ float4 up4(uint2 q) {            // 4 bf16 -> float4
    return make_float4(__uint_as_float(q.x << 16),
                       __uint_as_float(q.x & 0xFFFF0000u),
                       __uint_as_float(q.y << 16),
                       __uint_as_float(q.y & 0xFFFF0000u));
}

__device__ __forceinline__ void fma4(float4& acc, const float4 a,
                                     const float4 w0, const float4 w1,
                                     const float4 w2, const float4 w3) {
    acc.x = fmaf(a.x, w0.x, fmaf(a.y, w1.x, fmaf(a.z, w2.x, fmaf(a.w, w3.x, acc.x))));
    acc.y = fmaf(a.x, w0.y, fmaf(a.y, w1.y, fmaf(a.z, w2.y, fmaf(a.w, w3.y, acc.y))));
    acc.z = fmaf(a.x, w0.z, fmaf(a.y, w1.z, fmaf(a.z, w2.z, fmaf(a.w, w3.z, acc.z))));
    acc.w = fmaf(a.x, w0.w, fmaf(a.y, w1.w, fmaf(a.z, w2.w, fmaf(a.w, w3.w, acc.w))));
}

__device__ __forceinline__ float dot4(const float4 a, const float4 b) {
    return a.x * b.x + a.y * b.y + a.z * b.z + a.w * b.w;
}

// ---------------- FAT kernel: blocks 0..255 binscatter, rest gemm1 ----------------
// gemm1: 64x128 block tile, 8x4 register tile/thread, bf16 LDS.
// 48 KB overlay -> 3 blocks/CU for BOTH halves.
__global__ __launch_bounds__(256) void k_bin_gemm1(
    // binscatter args
    const int* __restrict__ src, const int* __restrict__ dst,
    int* __restrict__ cursor_g, unsigned int* __restrict__ binned,
    // gemm1 args
    const float* __restrict__ x, const float* __restrict__ W1,
    const float* __restrict__ a_src, const float* __restrict__ a_dst,
    unsigned short* __restrict__ h1b, float* __restrict__ al_src,
    float* __restrict__ al_dst)
{
    __shared__ __align__(16) unsigned char smem[49152];   // 48 KB overlay
    const int tid = threadIdx.x;

    if (blockIdx.x < NBKT) {
        // ---- binscatter with in-LDS histogram + global range reservation ----
        int* dstc = (int*)smem;               // 3125 ints (12.5 KB): cached dst
        int* cnt  = (int*)(smem + 12512);     // 256 ints
        int* cur  = (int*)(smem + 13536);     // 256 ints
        const int blk = blockIdx.x;
        const int e0  = blk * EPB;
        cnt[tid] = 0;
        __syncthreads();
        for (int j = tid; j < EPB; j += 256) {
            int d = dst[e0 + j];
            dstc[j] = d;
            atomicAdd(&cnt[d / NPB], 1);
        }
        __syncthreads();
        const int c = cnt[tid];
        int base = c ? atomicAdd(&cursor_g[tid], c) : 0;   // reserve range
        cur[tid] = tid * CAP + base;
        __syncthreads();
        for (int j = tid; j < EPB; j += 256) {
            int d   = dstc[j];
            int bkt = d / NPB;
            int dl  = d - bkt * NPB;
            int pos = atomicAdd(&cur[bkt], 1);
            binned[pos] = (unsigned int)src[e0 + j] | ((unsigned int)dl << 18);
        }
        return;
    }

    // ---- gemm1: 64 rows x 128 cols, 8x4 per thread, bf16 LDS ----
    uint2* xs = (uint2*)smem;                 // 16 KB: [row][g], g = 4-k granule
    uint2* ws = (uint2*)(smem + 16384);       // 32 KB: [k][cg], cg = 4-col granule
    const int bid  = (int)blockIdx.x - NBKT;
    const int row0 = bid * 64;
    const int tc   = tid & 31;                // col granule: cols tc*4 .. +3
    const int tr   = tid >> 5;                // row group: rows tr*8 .. +7
    const float4* x4  = (const float4*)x;
    const float4* W14 = (const float4*)W1;

    #pragma unroll
    for (int p = 0; p < 8; ++p) {             // x tile: 64 rows x 32 granules
        int i = tid + p * 256;
        int r = i >> 5, g = i & 31;
        int gr = row0 + r; if (gr > N_NODES - 1) gr = N_NODES - 1;
        float4 v = x4[gr * 32 + g];
        xs[r * 32 + g] = make_uint2(pack2bf(v.x, v.y), pack2bf(v.z, v.w));
    }
    #pragma unroll
    for (int p = 0; p < 16; ++p) {            // W: 128 k x 32 col-granules
        int i = tid + p * 256;
        int k = i >> 5, cg = i & 31;
        float4 v = W14[k * 32 + cg];
        ws[k * 32 + cg] = make_uint2(pack2bf(v.x, v.y), pack2bf(v.z, v.w));
    }
    __syncthreads();

    float4 acc[8];
    #pragma unroll
    for (int i = 0; i < 8; ++i) acc[i] = make_float4(0.f, 0.f, 0.f, 0.f);

    for (int k4 = 0; k4 < 32; ++k4) {         // 4 k per iteration
        float4 a4[8];
        #pragma unroll
        for (int i = 0; i < 8; ++i)
            a4[i] = up4(xs[(tr * 8 + i) * 32 + k4]);   // broadcast within half-wave
        #pragma unroll
        for (int kk = 0; kk < 4; ++kk) {
            float4 w = up4(ws[(k4 * 4 + kk) * 32 + tc]);
            #pragma unroll
            for (int i = 0; i < 8; ++i) {
                float a = (kk == 0) ? a4[i].x : (kk == 1) ? a4[i].y
                        : (kk == 2) ? a4[i].z : a4[i].w;
                acc[i].x = fmaf(a, w.x, acc[i].x);
                acc[i].y = fmaf(a, w.y, acc[i].y);
                acc[i].z = fmaf(a, w.z, acc[i].z);
                acc[i].w = fmaf(a, w.w, acc[i].w);
            }
        }
    }

    // epilogue: rows row0 + tr*8 + i, cols tc*4..+3 (head = tc>>2)
    const int head = tc >> 2;
    const float4 as4 = ((const float4*)a_src)[tc];
    const float4 ad4 = ((const float4*)a_dst)[tc];
    #pragma unroll
    for (int i = 0; i < 8; ++i) {
        int r = row0 + tr * 8 + i;
        float s = dot4(acc[i], as4);
        float d = dot4(acc[i], ad4);
        s += __shfl_xor(s, 1); s += __shfl_xor(s, 2);
        d += __shfl_xor(d, 1); d += __shfl_xor(d, 2);
        if (r < N_NODES) {
            ((uint2*)h1b)[r * 32 + tc] =
                make_uint2(pack2bf(acc[i].x, acc[i].y), pack2bf(acc[i].z, acc[i].w));
            if ((tc & 3) == 0) {
                al_src[r * 8 + head] = s;
                al_dst[r * 8 + head] = d;
            }
        }
    }
}

// ---------------- fine CSR per bucket (padded layout, row_beg/row_end) ----------------
__global__ __launch_bounds__(256) void k_csr_fine(const unsigned int* __restrict__ binned,
                                                  const int* __restrict__ cursor_g,
                                                  int* __restrict__ row_beg,
                                                  int* __restrict__ row_end,
                                                  int* __restrict__ csr) {
    __shared__ int cnt[256];
    __shared__ int sc[256];
    __shared__ int cur[256];
    const int b = blockIdx.x, tid = threadIdx.x;
    const int start = b * CAP;
    const int nE    = cursor_g[b];
    cnt[tid] = 0;
    __syncthreads();
    for (int j = tid; j < nE; j += 256)
        atomicAdd(&cnt[(binned[start + j] >> 18) & 255], 1);
    __syncthreads();
    const int v = cnt[tid];
    sc[tid] = v;
    __syncthreads();
    for (int off = 1; off < 256; off <<= 1) {
        int add = (tid >= off) ? sc[tid - off] : 0;
        __syncthreads();
        sc[tid] += add;
        __syncthreads();
    }
    const int excl = sc[tid] - v;
    cur[tid] = excl;
    const int node = b * NPB + tid;
    if (tid < NPB && node < N_NODES) {
        row_beg[node] = start + excl;
        row_end[node] = start + excl + v;
    }
    __syncthreads();
    for (int j = tid; j < nE; j += 256) {
        unsigned int p = binned[start + j];
        int dl  = (p >> 18) & 255;
        int pos = start + atomicAdd(&cur[dl], 1);
        csr[pos] = (int)(p & 0x3FFFFu);
    }
}

// ---------------- agg1: wave/node, 4 slots x 16 lanes x 16B, 2-wide pipeline ----------------
__global__ __launch_bounds__(256) void k_agg1(
    const unsigned short* __restrict__ h1b, const float* __restrict__ al_src,
    const float* __restrict__ al_dst, const int* __restrict__ row_beg,
    const int* __restrict__ row_end, const int* __restrict__ csr_src,
    const float* __restrict__ b1, float* __restrict__ h2)
{
    const int n = blockIdx.x * 4 + (threadIdx.x >> 6);
    const int l    = threadIdx.x & 63;
    const int slot = l >> 4;
    const int f2   = l & 15;
    const int head = f2 >> 1;
    const uint4* h1q = (const uint4*)h1b;    // 16 B = 8 bf16 feats

    const float alD = al_dst[n * 8 + head];
    float denom = 0.f;
    float acc[8];
    #pragma unroll
    for (int i = 0; i < 8; ++i) acc[i] = 0.f;

    if (slot == 0) {   // self loop
        float w = __expf(leaky(al_src[n * 8 + head] + alD));
        uint4 q = h1q[n * 16 + f2];
        float2 v0 = bf2f2(q.x), v1 = bf2f2(q.y), v2 = bf2f2(q.z), v3 = bf2f2(q.w);
        denom = w;
        acc[0] = w * v0.x; acc[1] = w * v0.y; acc[2] = w * v1.x; acc[3] = w * v1.y;
        acc[4] = w * v2.x; acc[5] = w * v2.y; acc[6] = w * v3.x; acc[7] = w * v3.y;
    }

    const int beg = row_beg[n], end = row_end[n];
    int j = beg + slot;
    for (; j + 4 < end; j += 8) {          // 2 edges per iteration, loads batched
        int sa = csr_src[j];
        int sb = csr_src[j + 4];
        float ala = al_src[sa * 8 + head];
        float alb = al_src[sb * 8 + head];
        uint4 qa = h1q[sa * 16 + f2];
        uint4 qb = h1q[sb * 16 + f2];
        float wa = __expf(leaky(ala + alD));
        float wb = __expf(leaky(alb + alD));
        denom += wa + wb;
        float2 v;
        v = bf2f2(qa.x); acc[0] = fmaf(wa, v.x, acc[0]); acc[1] = fmaf(wa, v.y, acc[1]);
        v = bf2f2(qa.y); acc[2] = fmaf(wa, v.x, acc[2]); acc[3] = fmaf(wa, v.y, acc[3]);
        v = bf2f2(qa.z); acc[4] = fmaf(wa, v.x, acc[4]); acc[5] = fmaf(wa, v.y, acc[5]);
        v = bf2f2(qa.w); acc[6] = fmaf(wa, v.x, acc[6]); acc[7] = fmaf(wa, v.y, acc[7]);
        v = bf2f2(qb.x); acc[0] = fmaf(wb, v.x, acc[0]); acc[1] = fmaf(wb, v.y, acc[1]);
        v = bf2f2(qb.y); acc[2] = fmaf(wb, v.x, acc[2]); acc[3] = fmaf(wb, v.y, acc[3]);
        v = bf2f2(qb.z); acc[4] = fmaf(wb, v.x, acc[4]); acc[5] = fmaf(wb, v.y, acc[5]);
        v = bf2f2(qb.w); acc[6] = fmaf(wb, v.x, acc[6]); acc[7] = fmaf(wb, v.y, acc[7]);
    }
    if (j < end) {                          // tail edge
        int s = csr_src[j];
        float w = __expf(leaky(al_src[s * 8 + head] + alD));
        uint4 q = h1q[s * 16 + f2];
        denom += w;
        float2 v;
        v = bf2f2(q.x); acc[0] = fmaf(w, v.x, acc[0]); acc[1] = fmaf(w, v.y, acc[1]);
        v = bf2f2(q.y); acc[2] = fmaf(w, v.x, acc[2]); acc[3] = fmaf(w, v.y, acc[3]);
        v = bf2f2(q.z); acc[4] = fmaf(w, v.x, acc[4]); acc[5] = fmaf(w, v.y, acc[5]);
        v = bf2f2(q.w); acc[6] = fmaf(w, v.x, acc[6]); acc[7] = fmaf(w, v.y, acc[7]);
    }

    #pragma unroll
    for (int i = 0; i < 8; ++i) {
        acc[i] += __shfl_xor(acc[i], 16);
        acc[i] += __shfl_xor(acc[i], 32);
    }
    denom += __shfl_xor(denom, 16);
    denom += __shfl_xor(denom, 32);

    if (slot == 0) {
        const float4 bA = ((const float4*)b1)[f2 * 2];
        const float4 bB = ((const float4*)b1)[f2 * 2 + 1];
        float inv = 1.f / denom;
        float o[8];
        o[0] = acc[0] * inv + bA.x; o[1] = acc[1] * inv + bA.y;
        o[2] = acc[2] * inv + bA.z; o[3] = acc[3] * inv + bA.w;
        o[4] = acc[4] * inv + bB.x; o[5] = acc[5] * inv + bB.y;
        o[6] = acc[6] * inv + bB.z; o[7] = acc[7] * inv + bB.w;
        #pragma unroll
        for (int i = 0; i < 8; ++i) o[i] = o[i] > 0.f ? o[i] : expm1f(o[i]);
        ((float4*)h2)[n * 32 + f2 * 2]     = make_float4(o[0], o[1], o[2], o[3]);
        ((float4*)h2)[n * 32 + f2 * 2 + 1] = make_float4(o[4], o[5], o[6], o[7]);
    }
}

// ---------------- GEMM2: t2(bf16) = h2 @ W2 (+ fused al2) ----------------
__global__ __launch_bounds__(128) void k_gemm2(
    const float* __restrict__ h2, const float* __restrict__ W2,
    const float* __restrict__ a_src, const float* __restrict__ a_dst,
    unsigned short* __restrict__ t2b, float* __restrict__ al_src,
    float* __restrict__ al_dst)
{
    __shared__ float4 xs4[64 * 32];  // 32 KB (swizzled)
    __shared__ float4 ws4[128 * 8];  // 16 KB
    const int tid  = threadIdx.x;
    const int row0 = (int)blockIdx.x * 64;
    const int tc   = tid & 7;
    const int tr   = tid >> 3;
    const float4* h24 = (const float4*)h2;
    const float4* W24 = (const float4*)W2;

    #pragma unroll
    for (int p = 0; p < 8; ++p) {
        int i = tid + p * 128;
        ws4[i] = W24[i];
    }
    #pragma unroll
    for (int p = 0; p < 16; ++p) {
        int i = tid + p * 128;
        int r = i >> 5, k4 = i & 31;
        int gr = row0 + r; if (gr > N_NODES - 1) gr = N_NODES - 1;
        xs4[r * 32 + (k4 ^ ((r >> 2) & 7))] = h24[gr * 32 + k4];
    }
    __syncthreads();

    float4 acc[4];
    #pragma unroll
    for (int i = 0; i < 4; ++i) acc[i] = make_float4(0.f, 0.f, 0.f, 0.f);
    const int sw = tr & 7;
    #pragma unroll 2
    for (int k4 = 0; k4 < 32; ++k4) {
        float4 w0 = ws4[(4 * k4 + 0) * 8 + tc];
        float4 w1 = ws4[(4 * k4 + 1) * 8 + tc];
        float4 w2 = ws4[(4 * k4 + 2) * 8 + tc];
        float4 w3 = ws4[(4 * k4 + 3) * 8 + tc];
        const int kk = k4 ^ sw;
        #pragma unroll
        for (int i = 0; i < 4; ++i) {
            float4 a = xs4[(4 * tr + i) * 32 + kk];
            fma4(acc[i], a, w0, w1, w2, w3);
        }
    }

    const float4 as4 = ((const float4*)a_src)[tc];
    const float4 ad4 = ((const float4*)a_dst)[tc];
    #pragma unroll
    for (int i = 0; i < 4; ++i) {
        int r = row0 + 4 * tr + i;
        if (r < N_NODES) {
            ((ushort4*)t2b)[r * 8 + tc] =
                make_ushort4(f2bf(acc[i].x), f2bf(acc[i].y),
                             f2bf(acc[i].z), f2bf(acc[i].w));
            float s = dot4(acc[i], as4);
            float d = dot4(acc[i], ad4);
            s += __shfl_xor(s, 1); s += __shfl_xor(s, 2); s += __shfl_xor(s, 4);
            d += __shfl_xor(d, 1); d += __shfl_xor(d, 2); d += __shfl_xor(d, 4);
            if (tc == 0) {
                al_src[r] = s;
                al_dst[r] = d;
            }
        }
    }
}

// ---------------- agg2: wave/node, 8 slots x 8 lanes x 8B, 2-wide ----------------
__global__ __launch_bounds__(256) void k_agg2(
    const unsigned short* __restrict__ t2b, const float* __restrict__ al_src,
    const float* __restrict__ al_dst, const int* __restrict__ row_beg,
    const int* __restrict__ row_end, const int* __restrict__ csr_src,
    const float* __restrict__ b2, float* __restrict__ out)
{
    const int n = blockIdx.x * 4 + (threadIdx.x >> 6);
    const int l = threadIdx.x & 63;
    const int slot = l >> 3;          // 8 edge slots
    const int f4   = l & 7;           // 4 classes per lane (uint2 of bf16x2)
    const uint2* t2u = (const uint2*)t2b;   // 8 B = 4 bf16

    const float alD = al_dst[n];
    float denom = 0.f;
    float4 acc = make_float4(0.f, 0.f, 0.f, 0.f);
    if (slot == 0) {                  // self loop
        float w = __expf(leaky(al_src[n] + alD));
        uint2 q = t2u[n * 8 + f4];
        float2 v0 = bf2f2(q.x), v1 = bf2f2(q.y);
        denom = w;
        acc = make_float4(w * v0.x, w * v0.y, w * v1.x, w * v1.y);
    }
    const int beg = row_beg[n], end = row_end[n];
    int j = beg + slot;
    for (; j + 8 < end; j += 16) {    // 2 edges per slot per iteration
        int sa = csr_src[j];
        int sb = csr_src[j + 8];
        float ala = al_src[sa];
        float alb = al_src[sb];
        uint2 qa = t2u[sa * 8 + f4];
        uint2 qb = t2u[sb * 8 + f4];
        float wa = __expf(leaky(ala + alD));
        float wb = __expf(leaky(alb + alD));
        denom += wa + wb;
        float2 v;
        v = bf2f2(qa.x); acc.x = fmaf(wa, v.x, acc.x); acc.y = fmaf(wa, v.y, acc.y);
        v = bf2f2(qa.y); acc.z = fmaf(wa, v.x, acc.z); acc.w = fmaf(wa, v.y, acc.w);
        v = bf2f2(qb.x); acc.x = fmaf(wb, v.x, acc.x); acc.y = fmaf(wb, v.y, acc.y);
        v = bf2f2(qb.y); acc.z = fmaf(wb, v.x, acc.z); acc.w = fmaf(wb, v.y, acc.w);
    }
    if (j < end) {
        int s = csr_src[j];
        float w = __expf(leaky(al_src[s] + alD));
        uint2 q = t2u[s * 8 + f4];
        denom += w;
        float2 v;
        v = bf2f2(q.x); acc.x = fmaf(w, v.x, acc.x); acc.y = fmaf(w, v.y, acc.y);
        v = bf2f2(q.y); acc.z = fmaf(w, v.x, acc.z); acc.w = fmaf(w, v.y, acc.w);
    }
    // reduce over the 8 slots (lane bits 3,4,5)
    #pragma unroll
    for (int off = 8; off <= 32; off <<= 1) {
        acc.x += __shfl_xor(acc.x, off); acc.y += __shfl_xor(acc.y, off);
        acc.z += __shfl_xor(acc.z, off); acc.w += __shfl_xor(acc.w, off);
        denom += __shfl_xor(denom, off);
    }

    const float4 bb = ((const float4*)b2)[f4];
    float inv = 1.f / denom;
    float o0 = acc.x * inv + bb.x;
    float o1 = acc.y * inv + bb.y;
    float o2 = acc.z * inv + bb.z;
    float o3 = acc.w * inv + bb.w;
    // log_softmax over 32 classes (8 lanes x 4 classes; lane bits 0..2)
    float m = fmaxf(fmaxf(o0, o1), fmaxf(o2, o3));
    for (int off = 1; off <= 4; off <<= 1) m = fmaxf(m, __shfl_xor(m, off));
    float ssum = __expf(o0 - m) + __expf(o1 - m) + __expf(o2 - m) + __expf(o3 - m);
    for (int off = 1; off <= 4; off <<= 1) ssum += __shfl_xor(ssum, off);
    float lg = m + __logf(ssum);
    if (slot == 0)
        ((float4*)out)[n * 8 + f4] = make_float4(o0 - lg, o1 - lg, o2 - lg, o3 - lg);
}

extern "C" void kernel_launch(void* const* d_in, const int* in_sizes, int n_in,
                              void* d_out, int out_size, void* d_ws, size_t ws_size,
                              hipStream_t stream) {
    const float* x      = (const float*)d_in[0];
    const int*   src    = (const int*)d_in[1];
    const int*   dst    = (const int*)d_in[2];
    const float* W1     = (const float*)d_in[3];
    const float* a_src1 = (const float*)d_in[4];
    const float* a_dst1 = (const float*)d_in[5];
    const float* b1     = (const float*)d_in[6];
    const float* W2     = (const float*)d_in[7];
    const float* a_src2 = (const float*)d_in[8];
    const float* a_dst2 = (const float*)d_in[9];
    const float* b2     = (const float*)d_in[10];
    float* out = (float*)d_out;

    char* ws = (char*)d_ws;
    size_t off = 0;
    auto alloc = [&](size_t bytes) {
        void* p = ws + off;
        off += (bytes + 255) & ~(size_t)255;
        return p;
    };
    unsigned short* h1b = (unsigned short*)alloc((size_t)N_NODES * 128 * 2);
    float*          h2  = (float*)alloc((size_t)N_NODES * 128 * 4);
    unsigned short* t2b = (unsigned short*)alloc((size_t)N_NODES * 32 * 2);
    float* alS1    = (float*)alloc((size_t)N_NODES * 8 * 4);
    float* alD1    = (float*)alloc((size_t)N_NODES * 8 * 4);
    float* alS2    = (float*)alloc((size_t)N_NODES * 4);
    float* alD2    = (float*)alloc((size_t)N_NODES * 4);
    int*   row_beg = (int*)alloc((size_t)N_NODES * 4);
    int*   row_end = (int*)alloc((size_t)N_NODES * 4);
    int*   csr     = (int*)alloc((size_t)NBKT * CAP * 4);      // 4 MB padded
    unsigned int* binned = (unsigned int*)alloc((size_t)NBKT * CAP * 4);  // 4 MB
    int*   cursor  = (int*)alloc((size_t)NBKT * 4);
    (void)ws_size; (void)in_sizes; (void)n_in; (void)out_size;

    const int row_tiles = (N_NODES + 63) / 64;   // 782 (gemm2)

    hipMemsetAsync(cursor, 0, (size_t)NBKT * 4, stream);
    k_bin_gemm1<<<NBKT + G1BLK, 256, 0, stream>>>(
        src, dst, cursor, binned,
        x, W1, a_src1, a_dst1, h1b, alS1, alD1);
    k_csr_fine<<<NBKT, 256, 0, stream>>>(binned, cursor, row_beg, row_end, csr);
    k_agg1<<<N_NODES / 4, 256, 0, stream>>>(h1b, alS1, alD1, row_beg, row_end, csr, b1, h2);
    k_gemm2<<<row_tiles, 128, 0, stream>>>(h2, W2, a_src2, a_dst2, t2b, alS2, alD2);
    k_agg2<<<N_NODES / 4, 256, 0, stream>>>(t2b, alS2, alD2, row_beg, row_end, csr, b2, out);
}

// Round 17
// 212.050 us; speedup vs baseline: 1.0257x; 1.0257x over previous
//
#include <hip/hip_runtime.h>

#define N_NODES   50000
#define N_EDGES   800000
#define NEG_SLOPE 0.2f
#define NBKT      256          // coarse buckets
#define NPB       196          // nodes per bucket (196*256 = 50176 >= 50000)
#define EPB       3125         // edges per binscatter block (800000/256)
#define CAP       4096         // fixed bucket capacity (true ~3136 +- 56; 17 sigma)
#define G1BLK     782          // gemm1 blocks: ceil(50000/64)

__device__ __forceinline__ float leaky(float x) {
    return x > 0.f ? x : x * NEG_SLOPE;
}

__device__ __forceinline__ unsigned short f2bf(float f) {   // RNE pack
    unsigned int u = __float_as_uint(f);
    unsigned int r = (u + 0x7FFFu + ((u >> 16) & 1u)) >> 16;
    return (unsigned short)r;
}

__device__ __forceinline__ unsigned int pack2bf(float a, float b) {
    return (unsigned int)f2bf(a) | ((unsigned int)f2bf(b) << 16);
}

__device__ __forceinline__ float2 bf2f2(unsigned int p) {   // packed bf16x2 -> float2
    return make_float2(__uint_as_float(p << 16),
                       __uint_as_float(p & 0xFFFF0000u));
}

__device__ __forceinline__ float4 up4(uint2 q) {            // 4 bf16 -> float4
    return make_float4(__uint_as_float(q.x << 16),
                       __uint_as_float(q.x & 0xFFFF0000u),
                       __uint_as_float(q.y << 16),
                       __uint_as_float(q.y & 0xFFFF0000u));
}

__device__ __forceinline__ float dot4(const float4 a, const float4 b) {
    return a.x * b.x + a.y * b.y + a.z * b.z + a.w * b.w;
}

// ---------------- FAT kernel: blocks 0..255 binscatter, rest gemm1 ----------------
// gemm1: 64x128 block tile, 8x4 register tile/thread, bf16 LDS. 48 KB overlay.
__global__ __launch_bounds__(256) void k_bin_gemm1(
    // binscatter args
    const int* __restrict__ src, const int* __restrict__ dst,
    int* __restrict__ cursor_g, unsigned int* __restrict__ binned,
    // gemm1 args
    const float* __restrict__ x, const float* __restrict__ W1,
    const float* __restrict__ a_src, const float* __restrict__ a_dst,
    unsigned short* __restrict__ h1b, float* __restrict__ al_src,
    float* __restrict__ al_dst)
{
    __shared__ __align__(16) unsigned char smem[49152];   // 48 KB overlay
    const int tid = threadIdx.x;

    if (blockIdx.x < NBKT) {
        // ---- binscatter with in-LDS histogram + global range reservation ----
        int* dstc = (int*)smem;               // 3125 ints (12.5 KB): cached dst
        int* cnt  = (int*)(smem + 12512);     // 256 ints
        int* cur  = (int*)(smem + 13536);     // 256 ints
        const int blk = blockIdx.x;
        const int e0  = blk * EPB;
        cnt[tid] = 0;
        __syncthreads();
        for (int j = tid; j < EPB; j += 256) {
            int d = dst[e0 + j];
            dstc[j] = d;
            atomicAdd(&cnt[d / NPB], 1);
        }
        __syncthreads();
        const int c = cnt[tid];
        int base = c ? atomicAdd(&cursor_g[tid], c) : 0;   // reserve range
        cur[tid] = tid * CAP + base;
        __syncthreads();
        for (int j = tid; j < EPB; j += 256) {
            int d   = dstc[j];
            int bkt = d / NPB;
            int dl  = d - bkt * NPB;
            int pos = atomicAdd(&cur[bkt], 1);
            binned[pos] = (unsigned int)src[e0 + j] | ((unsigned int)dl << 18);
        }
        return;
    }

    // ---- gemm1: 64 rows x 128 cols, 8x4 per thread, bf16 LDS ----
    uint2* xs = (uint2*)smem;                 // 16 KB: [row][g], g = 4-k granule
    uint2* ws = (uint2*)(smem + 16384);       // 32 KB: [k][cg], cg = 4-col granule
    const int bid  = (int)blockIdx.x - NBKT;
    const int row0 = bid * 64;
    const int tc   = tid & 31;                // col granule: cols tc*4 .. +3
    const int tr   = tid >> 5;                // row group: rows tr*8 .. +7
    const float4* x4  = (const float4*)x;
    const float4* W14 = (const float4*)W1;

    #pragma unroll
    for (int p = 0; p < 8; ++p) {             // x tile: 64 rows x 32 granules
        int i = tid + p * 256;
        int r = i >> 5, g = i & 31;
        int gr = row0 + r; if (gr > N_NODES - 1) gr = N_NODES - 1;
        float4 v = x4[gr * 32 + g];
        xs[r * 32 + g] = make_uint2(pack2bf(v.x, v.y), pack2bf(v.z, v.w));
    }
    #pragma unroll
    for (int p = 0; p < 16; ++p) {            // W: 128 k x 32 col-granules
        int i = tid + p * 256;
        int k = i >> 5, cg = i & 31;
        float4 v = W14[k * 32 + cg];
        ws[k * 32 + cg] = make_uint2(pack2bf(v.x, v.y), pack2bf(v.z, v.w));
    }
    __syncthreads();

    float4 acc[8];
    #pragma unroll
    for (int i = 0; i < 8; ++i) acc[i] = make_float4(0.f, 0.f, 0.f, 0.f);

    for (int k4 = 0; k4 < 32; ++k4) {         // 4 k per iteration
        float4 a4[8];
        #pragma unroll
        for (int i = 0; i < 8; ++i)
            a4[i] = up4(xs[(tr * 8 + i) * 32 + k4]);
        #pragma unroll
        for (int kk = 0; kk < 4; ++kk) {
            float4 w = up4(ws[(k4 * 4 + kk) * 32 + tc]);
            #pragma unroll
            for (int i = 0; i < 8; ++i) {
                float a = (kk == 0) ? a4[i].x : (kk == 1) ? a4[i].y
                        : (kk == 2) ? a4[i].z : a4[i].w;
                acc[i].x = fmaf(a, w.x, acc[i].x);
                acc[i].y = fmaf(a, w.y, acc[i].y);
                acc[i].z = fmaf(a, w.z, acc[i].z);
                acc[i].w = fmaf(a, w.w, acc[i].w);
            }
        }
    }

    const int head = tc >> 2;
    const float4 as4 = ((const float4*)a_src)[tc];
    const float4 ad4 = ((const float4*)a_dst)[tc];
    #pragma unroll
    for (int i = 0; i < 8; ++i) {
        int r = row0 + tr * 8 + i;
        float s = dot4(acc[i], as4);
        float d = dot4(acc[i], ad4);
        s += __shfl_xor(s, 1); s += __shfl_xor(s, 2);
        d += __shfl_xor(d, 1); d += __shfl_xor(d, 2);
        if (r < N_NODES) {
            ((uint2*)h1b)[r * 32 + tc] =
                make_uint2(pack2bf(acc[i].x, acc[i].y), pack2bf(acc[i].z, acc[i].w));
            if ((tc & 3) == 0) {
                al_src[r * 8 + head] = s;
                al_dst[r * 8 + head] = d;
            }
        }
    }
}

// ---------------- fine CSR per bucket (padded layout, row_beg/row_end) ----------------
__global__ __launch_bounds__(256) void k_csr_fine(const unsigned int* __restrict__ binned,
                                                  const int* __restrict__ cursor_g,
                                                  int* __restrict__ row_beg,
                                                  int* __restrict__ row_end,
                                                  int* __restrict__ csr) {
    __shared__ int cnt[256];
    __shared__ int sc[256];
    __shared__ int cur[256];
    const int b = blockIdx.x, tid = threadIdx.x;
    const int start = b * CAP;
    const int nE    = cursor_g[b];
    cnt[tid] = 0;
    __syncthreads();
    for (int j = tid; j < nE; j += 256)
        atomicAdd(&cnt[(binned[start + j] >> 18) & 255], 1);
    __syncthreads();
    const int v = cnt[tid];
    sc[tid] = v;
    __syncthreads();
    for (int off = 1; off < 256; off <<= 1) {
        int add = (tid >= off) ? sc[tid - off] : 0;
        __syncthreads();
        sc[tid] += add;
        __syncthreads();
    }
    const int excl = sc[tid] - v;
    cur[tid] = excl;
    const int node = b * NPB + tid;
    if (tid < NPB && node < N_NODES) {
        row_beg[node] = start + excl;
        row_end[node] = start + excl + v;
    }
    __syncthreads();
    for (int j = tid; j < nE; j += 256) {
        unsigned int p = binned[start + j];
        int dl  = (p >> 18) & 255;
        int pos = start + atomicAdd(&cur[dl], 1);
        csr[pos] = (int)(p & 0x3FFFFu);
    }
}

// ---------------- agg1+gemm2 fused: wave/node gather, then in-LDS 128->32 GEMM ----------------
// Main loop identical to R16 agg1. Epilogue: h2 row (regs) -> LDS -> t2(bf16) + al2.
__global__ __launch_bounds__(256) void k_agg1g2(
    const unsigned short* __restrict__ h1b, const float* __restrict__ al_src,
    const float* __restrict__ al_dst, const int* __restrict__ row_beg,
    const int* __restrict__ row_end, const int* __restrict__ csr_src,
    const float* __restrict__ b1, const float* __restrict__ W2,
    const float* __restrict__ a_src2, const float* __restrict__ a_dst2,
    unsigned short* __restrict__ t2b, float* __restrict__ alS2,
    float* __restrict__ alD2)
{
    __shared__ float w2s[128 * 32];   // 16 KB
    __shared__ float h2row[4][128];   // 2 KB
    const int tid  = threadIdx.x;
    const int wv   = tid >> 6;
    const int n    = blockIdx.x * 4 + wv;
    const int l    = tid & 63;
    const int slot = l >> 4;
    const int f2   = l & 15;
    const int head = f2 >> 1;
    const uint4* h1q = (const uint4*)h1b;    // 16 B = 8 bf16 feats

    #pragma unroll
    for (int p = 0; p < 16; ++p)             // stage W2 fp32 (used after barrier)
        w2s[tid + p * 256] = W2[tid + p * 256];

    const float alD = al_dst[n * 8 + head];
    float denom = 0.f;
    float acc[8];
    #pragma unroll
    for (int i = 0; i < 8; ++i) acc[i] = 0.f;

    if (slot == 0) {   // self loop
        float w = __expf(leaky(al_src[n * 8 + head] + alD));
        uint4 q = h1q[n * 16 + f2];
        float2 v0 = bf2f2(q.x), v1 = bf2f2(q.y), v2 = bf2f2(q.z), v3 = bf2f2(q.w);
        denom = w;
        acc[0] = w * v0.x; acc[1] = w * v0.y; acc[2] = w * v1.x; acc[3] = w * v1.y;
        acc[4] = w * v2.x; acc[5] = w * v2.y; acc[6] = w * v3.x; acc[7] = w * v3.y;
    }

    const int beg = row_beg[n], end = row_end[n];
    int j = beg + slot;
    for (; j + 4 < end; j += 8) {          // 2 edges per iteration, loads batched
        int sa = csr_src[j];
        int sb = csr_src[j + 4];
        float ala = al_src[sa * 8 + head];
        float alb = al_src[sb * 8 + head];
        uint4 qa = h1q[sa * 16 + f2];
        uint4 qb = h1q[sb * 16 + f2];
        float wa = __expf(leaky(ala + alD));
        float wb = __expf(leaky(alb + alD));
        denom += wa + wb;
        float2 v;
        v = bf2f2(qa.x); acc[0] = fmaf(wa, v.x, acc[0]); acc[1] = fmaf(wa, v.y, acc[1]);
        v = bf2f2(qa.y); acc[2] = fmaf(wa, v.x, acc[2]); acc[3] = fmaf(wa, v.y, acc[3]);
        v = bf2f2(qa.z); acc[4] = fmaf(wa, v.x, acc[4]); acc[5] = fmaf(wa, v.y, acc[5]);
        v = bf2f2(qa.w); acc[6] = fmaf(wa, v.x, acc[6]); acc[7] = fmaf(wa, v.y, acc[7]);
        v = bf2f2(qb.x); acc[0] = fmaf(wb, v.x, acc[0]); acc[1] = fmaf(wb, v.y, acc[1]);
        v = bf2f2(qb.y); acc[2] = fmaf(wb, v.x, acc[2]); acc[3] = fmaf(wb, v.y, acc[3]);
        v = bf2f2(qb.z); acc[4] = fmaf(wb, v.x, acc[4]); acc[5] = fmaf(wb, v.y, acc[5]);
        v = bf2f2(qb.w); acc[6] = fmaf(wb, v.x, acc[6]); acc[7] = fmaf(wb, v.y, acc[7]);
    }
    if (j < end) {                          // tail edge
        int s = csr_src[j];
        float w = __expf(leaky(al_src[s * 8 + head] + alD));
        uint4 q = h1q[s * 16 + f2];
        denom += w;
        float2 v;
        v = bf2f2(q.x); acc[0] = fmaf(w, v.x, acc[0]); acc[1] = fmaf(w, v.y, acc[1]);
        v = bf2f2(q.y); acc[2] = fmaf(w, v.x, acc[2]); acc[3] = fmaf(w, v.y, acc[3]);
        v = bf2f2(q.z); acc[4] = fmaf(w, v.x, acc[4]); acc[5] = fmaf(w, v.y, acc[5]);
        v = bf2f2(q.w); acc[6] = fmaf(w, v.x, acc[6]); acc[7] = fmaf(w, v.y, acc[7]);
    }

    #pragma unroll
    for (int i = 0; i < 8; ++i) {
        acc[i] += __shfl_xor(acc[i], 16);
        acc[i] += __shfl_xor(acc[i], 32);
    }
    denom += __shfl_xor(denom, 16);
    denom += __shfl_xor(denom, 32);

    // h2 row (bias + ELU) — all lanes compute; slot 0 writes to LDS
    {
        const float4 bA = ((const float4*)b1)[f2 * 2];
        const float4 bB = ((const float4*)b1)[f2 * 2 + 1];
        float inv = 1.f / denom;
        float o[8];
        o[0] = acc[0] * inv + bA.x; o[1] = acc[1] * inv + bA.y;
        o[2] = acc[2] * inv + bA.z; o[3] = acc[3] * inv + bA.w;
        o[4] = acc[4] * inv + bB.x; o[5] = acc[5] * inv + bB.y;
        o[6] = acc[6] * inv + bB.z; o[7] = acc[7] * inv + bB.w;
        #pragma unroll
        for (int i = 0; i < 8; ++i) o[i] = o[i] > 0.f ? o[i] : expm1f(o[i]);
        if (slot == 0) {
            *(float4*)&h2row[wv][f2 * 8]     = make_float4(o[0], o[1], o[2], o[3]);
            *(float4*)&h2row[wv][f2 * 8 + 4] = make_float4(o[4], o[5], o[6], o[7]);
        }
    }
    __syncthreads();   // W2 staged + all waves' h2 rows written

    // fused gemm2: lane = (k-half l>>5, class c = l&31)
    const int c  = l & 31;
    const int kh = l >> 5;
    const float* hr = h2row[wv];
    float sum = 0.f;
    #pragma unroll 8
    for (int k = kh * 64; k < kh * 64 + 64; ++k)
        sum = fmaf(hr[k], w2s[k * 32 + c], sum);
    sum += __shfl_xor(sum, 32);              // full t2[n][c]

    if (l < 32) t2b[n * 32 + c] = f2bf(sum);
    float s2 = sum * a_src2[c];
    float d2 = sum * a_dst2[c];
    #pragma unroll
    for (int off = 1; off <= 16; off <<= 1) {
        s2 += __shfl_xor(s2, off);
        d2 += __shfl_xor(d2, off);
    }
    if (l == 0) {
        alS2[n] = s2;
        alD2[n] = d2;
    }
}

// ---------------- agg2: wave/node, 8 slots x 8 lanes x 8B, 2-wide ----------------
__global__ __launch_bounds__(256) void k_agg2(
    const unsigned short* __restrict__ t2b, const float* __restrict__ al_src,
    const float* __restrict__ al_dst, const int* __restrict__ row_beg,
    const int* __restrict__ row_end, const int* __restrict__ csr_src,
    const float* __restrict__ b2, float* __restrict__ out)
{
    const int n = blockIdx.x * 4 + (threadIdx.x >> 6);
    const int l = threadIdx.x & 63;
    const int slot = l >> 3;          // 8 edge slots
    const int f4   = l & 7;           // 4 classes per lane (uint2 of bf16x2)
    const uint2* t2u = (const uint2*)t2b;   // 8 B = 4 bf16

    const float alD = al_dst[n];
    float denom = 0.f;
    float4 acc = make_float4(0.f, 0.f, 0.f, 0.f);
    if (slot == 0) {                  // self loop
        float w = __expf(leaky(al_src[n] + alD));
        uint2 q = t2u[n * 8 + f4];
        float2 v0 = bf2f2(q.x), v1 = bf2f2(q.y);
        denom = w;
        acc = make_float4(w * v0.x, w * v0.y, w * v1.x, w * v1.y);
    }
    const int beg = row_beg[n], end = row_end[n];
    int j = beg + slot;
    for (; j + 8 < end; j += 16) {    // 2 edges per slot per iteration
        int sa = csr_src[j];
        int sb = csr_src[j + 8];
        float ala = al_src[sa];
        float alb = al_src[sb];
        uint2 qa = t2u[sa * 8 + f4];
        uint2 qb = t2u[sb * 8 + f4];
        float wa = __expf(leaky(ala + alD));
        float wb = __expf(leaky(alb + alD));
        denom += wa + wb;
        float2 v;
        v = bf2f2(qa.x); acc.x = fmaf(wa, v.x, acc.x); acc.y = fmaf(wa, v.y, acc.y);
        v = bf2f2(qa.y); acc.z = fmaf(wa, v.x, acc.z); acc.w = fmaf(wa, v.y, acc.w);
        v = bf2f2(qb.x); acc.x = fmaf(wb, v.x, acc.x); acc.y = fmaf(wb, v.y, acc.y);
        v = bf2f2(qb.y); acc.z = fmaf(wb, v.x, acc.z); acc.w = fmaf(wb, v.y, acc.w);
    }
    if (j < end) {
        int s = csr_src[j];
        float w = __expf(leaky(al_src[s] + alD));
        uint2 q = t2u[s * 8 + f4];
        denom += w;
        float2 v;
        v = bf2f2(q.x); acc.x = fmaf(w, v.x, acc.x); acc.y = fmaf(w, v.y, acc.y);
        v = bf2f2(q.y); acc.z = fmaf(w, v.x, acc.z); acc.w = fmaf(w, v.y, acc.w);
    }
    // reduce over the 8 slots (lane bits 3,4,5)
    #pragma unroll
    for (int off = 8; off <= 32; off <<= 1) {
        acc.x += __shfl_xor(acc.x, off); acc.y += __shfl_xor(acc.y, off);
        acc.z += __shfl_xor(acc.z, off); acc.w += __shfl_xor(acc.w, off);
        denom += __shfl_xor(denom, off);
    }

    const float4 bb = ((const float4*)b2)[f4];
    float inv = 1.f / denom;
    float o0 = acc.x * inv + bb.x;
    float o1 = acc.y * inv + bb.y;
    float o2 = acc.z * inv + bb.z;
    float o3 = acc.w * inv + bb.w;
    // log_softmax over 32 classes (8 lanes x 4 classes; lane bits 0..2)
    float m = fmaxf(fmaxf(o0, o1), fmaxf(o2, o3));
    for (int off = 1; off <= 4; off <<= 1) m = fmaxf(m, __shfl_xor(m, off));
    float ssum = __expf(o0 - m) + __expf(o1 - m) + __expf(o2 - m) + __expf(o3 - m);
    for (int off = 1; off <= 4; off <<= 1) ssum += __shfl_xor(ssum, off);
    float lg = m + __logf(ssum);
    if (slot == 0)
        ((float4*)out)[n * 8 + f4] = make_float4(o0 - lg, o1 - lg, o2 - lg, o3 - lg);
}

extern "C" void kernel_launch(void* const* d_in, const int* in_sizes, int n_in,
                              void* d_out, int out_size, void* d_ws, size_t ws_size,
                              hipStream_t stream) {
    const float* x      = (const float*)d_in[0];
    const int*   src    = (const int*)d_in[1];
    const int*   dst    = (const int*)d_in[2];
    const float* W1     = (const float*)d_in[3];
    const float* a_src1 = (const float*)d_in[4];
    const float* a_dst1 = (const float*)d_in[5];
    const float* b1     = (const float*)d_in[6];
    const float* W2     = (const float*)d_in[7];
    const float* a_src2 = (const float*)d_in[8];
    const float* a_dst2 = (const float*)d_in[9];
    const float* b2     = (const float*)d_in[10];
    float* out = (float*)d_out;

    char* ws = (char*)d_ws;
    size_t off = 0;
    auto alloc = [&](size_t bytes) {
        void* p = ws + off;
        off += (bytes + 255) & ~(size_t)255;
        return p;
    };
    unsigned short* h1b = (unsigned short*)alloc((size_t)N_NODES * 128 * 2);
    unsigned short* t2b = (unsigned short*)alloc((size_t)N_NODES * 32 * 2);
    float* alS1    = (float*)alloc((size_t)N_NODES * 8 * 4);
    float* alD1    = (float*)alloc((size_t)N_NODES * 8 * 4);
    float* alS2    = (float*)alloc((size_t)N_NODES * 4);
    float* alD2    = (float*)alloc((size_t)N_NODES * 4);
    int*   row_beg = (int*)alloc((size_t)N_NODES * 4);
    int*   row_end = (int*)alloc((size_t)N_NODES * 4);
    int*   csr     = (int*)alloc((size_t)NBKT * CAP * 4);      // 4 MB padded
    unsigned int* binned = (unsigned int*)alloc((size_t)NBKT * CAP * 4);  // 4 MB
    int*   cursor  = (int*)alloc((size_t)NBKT * 4);
    (void)ws_size; (void)in_sizes; (void)n_in; (void)out_size;

    hipMemsetAsync(cursor, 0, (size_t)NBKT * 4, stream);
    k_bin_gemm1<<<NBKT + G1BLK, 256, 0, stream>>>(
        src, dst, cursor, binned,
        x, W1, a_src1, a_dst1, h1b, alS1, alD1);
    k_csr_fine<<<NBKT, 256, 0, stream>>>(binned, cursor, row_beg, row_end, csr);
    k_agg1g2<<<N_NODES / 4, 256, 0, stream>>>(
        h1b, alS1, alD1, row_beg, row_end, csr,
        b1, W2, a_src2, a_dst2, t2b, alS2, alD2);
    k_agg2<<<N_NODES / 4, 256, 0, stream>>>(t2b, alS2, alD2, row_beg, row_end, csr, b2, out);
}